// Round 5
// baseline (611.381 us; speedup 1.0000x reference)
//
#include <hip/hip_runtime.h>
#include <hip/hip_cooperative_groups.h>
#include <stdint.h>

namespace cg = cooperative_groups;

typedef unsigned int u32;
typedef unsigned long long u64;

#define BATCH 16
#define NANCH 25200
#define NCLS 80
#define ROWF 85
#define MAXC 1000
#define CONF_T 0.25f
#define IOU_T 0.45f
#define EPS_F 1e-7f
#define TILE2 128
#define TPB2 ((NANCH + TILE2 - 1) / TILE2)     /* 197 tiles per batch */
#define NTILE2TOT (BATCH * TPB2)               /* 3152 */

// IoU exactly as the numpy/JAX reference computes it (no FMA contraction:
// keep inter's rounding separate from the union subtraction).
__device__ __forceinline__ float iou_ref(float4 a, float4 b) {
#pragma clang fp contract(off)
  float ai = (a.z - a.x) * (a.w - a.y);
  float aj = (b.z - b.x) * (b.w - b.y);
  float ltx = fmaxf(a.x, b.x), lty = fmaxf(a.y, b.y);
  float rbx = fminf(a.z, b.z), rby = fminf(a.w, b.w);
  float wx = fmaxf(rbx - ltx, 0.0f), wy = fmaxf(rby - lty, 0.0f);
  float inter = wx * wy;
  return inter / (ai + aj - inter + EPS_F);
}

// ---- Phase 1: score one 128-anchor tile (1024 threads), emit keys ----
// key = ordered(score)<<32 | (32767-n)<<7 | cls (desc score, ties asc index)
__device__ __forceinline__ void phase1_tile(const float* __restrict__ pred,
                                            u64* __restrict__ keys,
                                            int tile, int tid,
                                            float* srow, u64* skeys2) {
  int b = tile / TPB2;
  int ti = tile % TPB2;
  int t0 = ti * TILE2;
  int ntile = (t0 + TILE2 <= NANCH) ? TILE2 : (NANCH - t0);   // 128 or 112
  int nf4 = (ntile * ROWF) >> 2;                              // 2720 or 2380
  const float4* src4 = (const float4*)(pred + ((size_t)b * NANCH + t0) * ROWF);
  float4* smem4 = (float4*)srow;
  __syncthreads();                       // protect LDS reuse across tiles
  for (int i = tid; i < nf4; i += 1024) smem4[i] = src4[i];
  __syncthreads();
  int a = tid >> 3;                      // anchor in tile (0..127)
  int q = tid & 7;                       // 8 threads/anchor, 10 classes each
  float best = -1e30f;
  int bidx = 0;
  float obj = 0.0f;
  if (a < ntile) {
    const float* row = srow + a * ROWF;
    obj = row[4];
    int c0 = q * 10;
#pragma unroll
    for (int c = 0; c < 10; ++c) {
      float s = row[5 + c0 + c] * obj;   // exact same mul as reference
      if (s > best) { best = s; bidx = c0 + c; }
    }
  }
  // exact tie rule: larger score wins; equal -> lower class index wins
#pragma unroll
  for (int off = 1; off < 8; off <<= 1) {
    float ob = __shfl_xor(best, off);
    int oi = __shfl_xor(bidx, off);
    if (ob > best || (ob == best && oi < bidx)) { best = ob; bidx = oi; }
  }
  if (q == 0 && a < ntile) {
    int n = t0 + a;
    bool valid = (obj > CONF_T) && (best > CONF_T);
    u32 hi = valid ? (__float_as_uint(best) | 0x80000000u)   // ordered-float
                   : (((u32)n * 2654435761u) >> 1);          // spread, <0x8000..
    u32 lo = ((u32)(32767 - n) << 7) | (u32)bidx;
    skeys2[a] = ((u64)hi << 32) | lo;
  }
  __syncthreads();
  if (tid < ntile) keys[(size_t)b * NANCH + t0 + tid] = skeys2[tid];
}

// ---- Phase 2: exact top-1000 for batch b. Radix 12+12+8 (self-hist), ----
// MLP-4 scans, two-level suffix select, compact, bitonic 2048, epilogue.
__device__ __forceinline__ void phase2_impl(const float* __restrict__ pred,
                                            const u64* __restrict__ keys,
                                            float* __restrict__ selbox,
                                            float* __restrict__ offbox,
                                            float* __restrict__ selconf,
                                            float* __restrict__ selcls,
                                            u32* __restrict__ selvalid,
                                            int b, int tid,
                                            u32* h4, u64* skey, u32* wsum,
                                            u32* sh_sel, int* sh_rank,
                                            u32* scount) {
  int wv = tid >> 6, lane = tid & 63;
  const u64* kb = keys + (size_t)b * NANCH;
  u32 prefix = 0;
  // two 12-bit rounds
  for (int r = 0; r < 2; ++r) {
    for (int i = tid; i < 4096; i += 1024) h4[i] = 0;
    __syncthreads();
    for (int i0 = tid; i0 < NANCH; i0 += 4096) {
      int j1 = i0 + 1024, j2 = i0 + 2048, j3 = i0 + 3072;
      u64 k0 = kb[i0];
      u64 k1v = (j1 < NANCH) ? kb[j1] : 0;
      u64 k2v = (j2 < NANCH) ? kb[j2] : 0;
      u64 k3v = (j3 < NANCH) ? kb[j3] : 0;
      u32 h0 = (u32)(k0 >> 32), h1 = (u32)(k1v >> 32);
      u32 h2 = (u32)(k2v >> 32), h3 = (u32)(k3v >> 32);
      if (r == 0) {
        atomicAdd(&h4[h0 >> 20], 1u);
        if (j1 < NANCH) atomicAdd(&h4[h1 >> 20], 1u);
        if (j2 < NANCH) atomicAdd(&h4[h2 >> 20], 1u);
        if (j3 < NANCH) atomicAdd(&h4[h3 >> 20], 1u);
      } else {
        if ((h0 >> 20) == prefix) atomicAdd(&h4[(h0 >> 8) & 0xFFFu], 1u);
        if (j1 < NANCH && (h1 >> 20) == prefix) atomicAdd(&h4[(h1 >> 8) & 0xFFFu], 1u);
        if (j2 < NANCH && (h2 >> 20) == prefix) atomicAdd(&h4[(h2 >> 8) & 0xFFFu], 1u);
        if (j3 < NANCH && (h3 >> 20) == prefix) atomicAdd(&h4[(h3 >> 8) & 0xFFFu], 1u);
      }
    }
    __syncthreads();
    u32 a0 = h4[4 * tid], a1 = h4[4 * tid + 1], a2 = h4[4 * tid + 2], a3 = h4[4 * tid + 3];
    u32 lsum = a0 + a1 + a2 + a3;
    u32 suf = lsum;
#pragma unroll
    for (int off = 1; off < 64; off <<= 1) {
      u32 tv = __shfl_down(suf, off);
      if (lane + off < 64) suf += tv;
    }
    if (lane == 0) wsum[wv] = suf;
    int rank = (r == 0) ? MAXC : *sh_rank;   // read BEFORE writers update
    __syncthreads();
    u32 base = 0;
#pragma unroll
    for (int w2 = 0; w2 < 16; ++w2) if (w2 > wv) base += wsum[w2];
    u32 e3 = base + suf - lsum; u32 i3v = e3 + a3;
    u32 e2 = i3v;               u32 i2v = e2 + a2;
    u32 e1 = i2v;               u32 i1v = e1 + a1;
    u32 e0 = i1v;               u32 i0v = e0 + a0;
    if ((int)i3v >= rank && (int)e3 < rank) { *sh_sel = 4u*tid+3u; *sh_rank = rank-(int)e3; }
    if ((int)i2v >= rank && (int)e2 < rank) { *sh_sel = 4u*tid+2u; *sh_rank = rank-(int)e2; }
    if ((int)i1v >= rank && (int)e1 < rank) { *sh_sel = 4u*tid+1u; *sh_rank = rank-(int)e1; }
    if ((int)i0v >= rank && (int)e0 < rank) { *sh_sel = 4u*tid+0u; *sh_rank = rank-(int)e0; }
    __syncthreads();
    prefix = (prefix << 12) | *sh_sel;
  }
  // final 8-bit round (256 bins, wave-0 select)
  if (tid < 256) h4[tid] = 0;
  __syncthreads();
  for (int i0 = tid; i0 < NANCH; i0 += 4096) {
    int j1 = i0 + 1024, j2 = i0 + 2048, j3 = i0 + 3072;
    u64 k0 = kb[i0];
    u64 k1v = (j1 < NANCH) ? kb[j1] : 0;
    u64 k2v = (j2 < NANCH) ? kb[j2] : 0;
    u64 k3v = (j3 < NANCH) ? kb[j3] : 0;
    u32 h0 = (u32)(k0 >> 32), h1 = (u32)(k1v >> 32);
    u32 h2 = (u32)(k2v >> 32), h3 = (u32)(k3v >> 32);
    if ((h0 >> 8) == prefix) atomicAdd(&h4[h0 & 0xFFu], 1u);
    if (j1 < NANCH && (h1 >> 8) == prefix) atomicAdd(&h4[h1 & 0xFFu], 1u);
    if (j2 < NANCH && (h2 >> 8) == prefix) atomicAdd(&h4[h2 & 0xFFu], 1u);
    if (j3 < NANCH && (h3 >> 8) == prefix) atomicAdd(&h4[h3 & 0xFFu], 1u);
  }
  __syncthreads();
  if (tid < 64) {
    int l = tid;
    u32 a0 = h4[4 * l], a1 = h4[4 * l + 1], a2 = h4[4 * l + 2], a3 = h4[4 * l + 3];
    u32 lsum = a0 + a1 + a2 + a3;
    u32 suf = lsum;
#pragma unroll
    for (int off = 1; off < 64; off <<= 1) {
      u32 tv = __shfl_down(suf, off);
      if (l + off < 64) suf += tv;
    }
    int rank = *sh_rank;          // intra-wave: reads precede writes in order
    u32 e3 = suf - lsum; u32 i3v = e3 + a3;
    u32 e2 = i3v;        u32 i2v = e2 + a2;
    u32 e1 = i2v;        u32 i1v = e1 + a1;
    u32 e0 = i1v;        u32 i0v = e0 + a0;
    if ((int)i3v >= rank && (int)e3 < rank) { *sh_sel = 4u*l+3u; }
    if ((int)i2v >= rank && (int)e2 < rank) { *sh_sel = 4u*l+2u; }
    if ((int)i1v >= rank && (int)e1 < rank) { *sh_sel = 4u*l+1u; }
    if ((int)i0v >= rank && (int)e0 < rank) { *sh_sel = 4u*l+0u; }
  }
  __syncthreads();
  u32 Cstar = (prefix << 8) | *sh_sel;

  // compact (MLP-4)
  if (tid == 0) *scount = 0;
  skey[tid] = ~0ull;
  skey[tid + 1024] = ~0ull;
  __syncthreads();
  for (int i0 = tid; i0 < NANCH; i0 += 4096) {
    int j1 = i0 + 1024, j2 = i0 + 2048, j3 = i0 + 3072;
    u64 k0 = kb[i0];
    u64 k1v = (j1 < NANCH) ? kb[j1] : 0;
    u64 k2v = (j2 < NANCH) ? kb[j2] : 0;
    u64 k3v = (j3 < NANCH) ? kb[j3] : 0;
    if ((u32)(k0 >> 32) >= Cstar) { u32 p = atomicAdd(scount, 1u); if (p < 2048) skey[p] = ~k0; }
    if (j1 < NANCH && (u32)(k1v >> 32) >= Cstar) { u32 p = atomicAdd(scount, 1u); if (p < 2048) skey[p] = ~k1v; }
    if (j2 < NANCH && (u32)(k2v >> 32) >= Cstar) { u32 p = atomicAdd(scount, 1u); if (p < 2048) skey[p] = ~k2v; }
    if (j3 < NANCH && (u32)(k3v >> 32) >= Cstar) { u32 p = atomicAdd(scount, 1u); if (p < 2048) skey[p] = ~k3v; }
  }
  __syncthreads();
  // bitonic sort 2048 (ascending on ~key == descending key)
  for (u32 kk = 2; kk <= 2048; kk <<= 1) {
    for (u32 j = kk >> 1; j > 0; j >>= 1) {
      for (int idx = tid; idx < 2048; idx += 1024) {
        u32 ixj = (u32)idx ^ j;
        if (ixj > (u32)idx) {
          u64 a = skey[idx], c2 = skey[ixj];
          bool up = ((idx & kk) == 0);
          if (up ? (a > c2) : (a < c2)) { skey[idx] = c2; skey[ixj] = a; }
        }
      }
      __syncthreads();
    }
  }
  // epilogue: gather + xywh2xyxy + class-offset boxes
  if (tid < MAXC) {
    u64 k = ~skey[tid];
    u32 hi = (u32)(k >> 32);
    u32 lo = (u32)k;
    u32 n = 32767u - (lo >> 7);
    u32 ci = lo & 127u;
    bool valid = hi > 0x80000000u;
    float conf = valid ? __uint_as_float(hi & 0x7FFFFFFFu) : 0.0f;
    const float* pr = pred + ((size_t)b * NANCH + n) * ROWF;
    float x = pr[0], y = pr[1], w = pr[2], h2 = pr[3];
    float x1 = x - w * 0.5f, y1 = y - h2 * 0.5f;
    float x2 = x + w * 0.5f, y2 = y + h2 * 0.5f;
    float cf = (float)ci;
    float off = cf * 4096.0f;
    int o = b * MAXC + tid;
    ((float4*)selbox)[o] = make_float4(x1, y1, x2, y2);
    ((float4*)offbox)[o] = make_float4(x1 + off, y1 + off, x2 + off, y2 + off);
    selconf[o] = conf;
    selcls[o] = cf;
    selvalid[o] = valid ? 1u : 0u;
  }
}

// ---- Phase 3: one wave computes one transposed-suppression row ----
__device__ __forceinline__ void phase3_row(const float4* __restrict__ offbox4,
                                           u64* __restrict__ dt,
                                           int row, int lane) {
  int b = row / MAXC;
  int i = row % MAXC;
  float4 bi = offbox4[b * MAXC + i];
  u64 myword = 0;
  for (int w = 0; w < 16; ++w) {
    int j = w * 64 + lane;
    int jc = (j < MAXC) ? j : 0;
    float4 bj = offbox4[b * MAXC + jc];
    float iou = iou_ref(bi, bj);
    bool bit = (iou > IOU_T) && (j < i);
    u64 bal = __ballot(bit ? 1 : 0);
    if (lane == w) myword = bal;
  }
  if (lane < 16) dt[((size_t)b * 16 + lane) * MAXC + i] = myword;  // word-major
}

// ---- Phase 4: Jacobi fixed-point NMS + output (one block per batch) ----
__device__ __forceinline__ void phase4_impl(const u64* __restrict__ dt,
                                            const u32* __restrict__ selvalid,
                                            const float* __restrict__ selbox,
                                            const float* __restrict__ selconf,
                                            const float* __restrict__ selcls,
                                            float* __restrict__ out,
                                            int b, int tid,
                                            u64* keepv, u32* changed) {
  int wv = tid >> 6, lane = tid & 63;
  bool valid = false;
  u64 dtr[16];
  if (tid < MAXC) {
    valid = selvalid[b * MAXC + tid] != 0u;
#pragma unroll
    for (int w = 0; w < 16; ++w) dtr[w] = dt[((size_t)b * 16 + w) * MAXC + tid];
  } else {
#pragma unroll
    for (int w = 0; w < 16; ++w) dtr[w] = 0ull;
  }
  u64 bal0 = __ballot(valid ? 1 : 0);
  if (tid == 0) *changed = 0;
  if (lane == 0) keepv[wv] = bal0;
  __syncthreads();
  for (int pass = 0; pass < MAXC; ++pass) {
    u64 kv[16];
#pragma unroll
    for (int w = 0; w < 16; ++w) kv[w] = keepv[w];
    u64 s = 0;
#pragma unroll
    for (int w = 0; w < 16; ++w) s |= dtr[w] & kv[w];
    bool nk = valid && (s == 0ull);
    u64 bal = __ballot(nk ? 1 : 0);
    __syncthreads();                       // A: all keepv reads done
    if (lane == 0 && bal != kv[wv]) { keepv[wv] = bal; atomicOr(changed, 1u); }
    __syncthreads();                       // B: writes visible
    u32 ch = *changed;
    __syncthreads();                       // C: all read ch before reset
    if (tid == 0) *changed = 0;
    if (!ch) break;                        // ch uniform -> uniform exit
  }
  if (tid < MAXC) {
    bool kept = ((keepv[wv] >> lane) & 1ull) != 0ull;
    size_t o = (size_t)b * MAXC + tid;
    float4 bx = ((const float4*)selbox)[o];
    float cf = selconf[o], cl = selcls[o];
    float* orow = out + o * 6;
    orow[0] = kept ? bx.x : 0.0f;
    orow[1] = kept ? bx.y : 0.0f;
    orow[2] = kept ? bx.z : 0.0f;
    orow[3] = kept ? bx.w : 0.0f;
    orow[4] = kept ? cf : 0.0f;
    orow[5] = kept ? cl : 0.0f;
    out[(size_t)BATCH * MAXC * 6 + o] = kept ? 1.0f : 0.0f;
  }
}

// ==== Fused cooperative kernel: 256 blocks x 1024 threads (1 block/CU) ====
__global__ __launch_bounds__(1024) void fused_all(const float* __restrict__ pred,
                                                  u64* __restrict__ keys,
                                                  float* __restrict__ selbox,
                                                  float* __restrict__ offbox,
                                                  float* __restrict__ selconf,
                                                  float* __restrict__ selcls,
                                                  u32* __restrict__ selvalid,
                                                  u64* __restrict__ dt,
                                                  float* __restrict__ out) {
  cg::grid_group grid = cg::this_grid();
  __shared__ __align__(16) float srow[TILE2 * ROWF];   // 43520 B (aliased in P2)
  __shared__ u64 skeys2[TILE2];
  __shared__ u32 wsum[16];
  __shared__ u32 sh_sel; __shared__ int sh_rank; __shared__ u32 scount;
  __shared__ u64 keepv[16]; __shared__ u32 changed;
  int tid = threadIdx.x, bid = blockIdx.x;
  int lane = tid & 63;

  // P1: score + keys
  for (int tile = bid; tile < NTILE2TOT; tile += 256)
    phase1_tile(pred, keys, tile, tid, srow, skeys2);
  __threadfence();
  grid.sync();

  // P2: top-1000 select (16 active blocks)
  if (bid < BATCH) {
    u32* h4 = (u32*)srow;                 // 16 KB
    u64* skey = (u64*)(srow + 4096);      // 16 KB, 16-byte aligned offset
    phase2_impl(pred, keys, selbox, offbox, selconf, selcls, selvalid,
                bid, tid, h4, skey, wsum, &sh_sel, &sh_rank, &scount);
  }
  __threadfence();
  grid.sync();

  // P3: suppression matrix (4096 waves for 16000 rows)
  int gw = bid * 16 + (tid >> 6);
  for (int row = gw; row < BATCH * MAXC; row += 4096)
    phase3_row((const float4*)offbox, dt, row, lane);
  __threadfence();
  grid.sync();

  // P4: Jacobi NMS + output (16 active blocks)
  if (bid < BATCH)
    phase4_impl(dt, selvalid, selbox, selconf, selcls, out, bid, tid,
                keepv, &changed);
}

// ==== Fallback wrappers (used only if cooperative launch is rejected) ====
__global__ __launch_bounds__(1024) void k1f(const float* __restrict__ pred,
                                            u64* __restrict__ keys) {
  __shared__ __align__(16) float srow[TILE2 * ROWF];
  __shared__ u64 skeys2[TILE2];
  phase1_tile(pred, keys, blockIdx.x, threadIdx.x, srow, skeys2);
}
__global__ __launch_bounds__(1024) void k2f(const float* __restrict__ pred,
                                            const u64* __restrict__ keys,
                                            float* __restrict__ selbox,
                                            float* __restrict__ offbox,
                                            float* __restrict__ selconf,
                                            float* __restrict__ selcls,
                                            u32* __restrict__ selvalid) {
  __shared__ __align__(16) u32 h4[4096];
  __shared__ u64 skey[2048];
  __shared__ u32 wsum[16];
  __shared__ u32 sh_sel; __shared__ int sh_rank; __shared__ u32 scount;
  phase2_impl(pred, keys, selbox, offbox, selconf, selcls, selvalid,
              blockIdx.x, threadIdx.x, h4, skey, wsum, &sh_sel, &sh_rank, &scount);
}
__global__ __launch_bounds__(256) void k3f(const float4* __restrict__ offbox4,
                                           u64* __restrict__ dt) {
  int row = blockIdx.x * 4 + (threadIdx.x >> 6);
  phase3_row(offbox4, dt, row, threadIdx.x & 63);
}
__global__ __launch_bounds__(1024) void k4f(const u64* __restrict__ dt,
                                            const u32* __restrict__ selvalid,
                                            const float* __restrict__ selbox,
                                            const float* __restrict__ selconf,
                                            const float* __restrict__ selcls,
                                            float* __restrict__ out) {
  __shared__ u64 keepv[16]; __shared__ u32 changed;
  phase4_impl(dt, selvalid, selbox, selconf, selcls, out,
              blockIdx.x, threadIdx.x, keepv, &changed);
}

extern "C" void kernel_launch(void* const* d_in, const int* in_sizes, int n_in,
                              void* d_out, int out_size, void* d_ws, size_t ws_size,
                              hipStream_t stream) {
  const float* pred = (const float*)d_in[0];
  float* out = (float*)d_out;
  char* ws = (char*)d_ws;
  size_t off = 0;
  auto alloc = [&](size_t bytes) -> void* {
    void* p = ws + off;
    off = (off + bytes + 255) & ~(size_t)255;
    return p;
  };
  u64* keys     = (u64*)alloc((size_t)BATCH * NANCH * 8);
  float* selbox = (float*)alloc((size_t)BATCH * MAXC * 4 * 4);
  float* offbox = (float*)alloc((size_t)BATCH * MAXC * 4 * 4);
  float* selconf= (float*)alloc((size_t)BATCH * MAXC * 4);
  float* selcls = (float*)alloc((size_t)BATCH * MAXC * 4);
  u32* selvalid = (u32*)alloc((size_t)BATCH * MAXC * 4);
  u64* dt       = (u64*)alloc((size_t)BATCH * 16 * MAXC * 8);
  (void)ws_size; (void)in_sizes; (void)n_in; (void)out_size;

  void* args[] = {(void*)&pred, (void*)&keys, (void*)&selbox, (void*)&offbox,
                  (void*)&selconf, (void*)&selcls, (void*)&selvalid,
                  (void*)&dt, (void*)&out};
  hipError_t rc = hipLaunchCooperativeKernel((const void*)fused_all,
                                             dim3(256), dim3(1024),
                                             args, 0, stream);
  if (rc != hipSuccess) {
    // Fallback: identical work as 4 ordinary launches.
    k1f<<<NTILE2TOT, 1024, 0, stream>>>(pred, keys);
    k2f<<<BATCH, 1024, 0, stream>>>(pred, keys, selbox, offbox,
                                    selconf, selcls, selvalid);
    k3f<<<(BATCH * MAXC) / 4, 256, 0, stream>>>((const float4*)offbox, dt);
    k4f<<<BATCH, 1024, 0, stream>>>(dt, selvalid, selbox, selconf,
                                    selcls, out);
  }
}

// Round 6
// 269.560 us; speedup vs baseline: 2.2681x; 2.2681x over previous
//
#include <hip/hip_runtime.h>
#include <stdint.h>

typedef unsigned int u32;
typedef unsigned long long u64;

#define BATCH 16
#define NANCH 25200
#define NCLS 80
#define ROWF 85
#define MAXC 1000
#define CONF_T 0.25f
#define IOU_T 0.45f
#define EPS_F 1e-7f
#define TILE 64
#define NTILES ((NANCH + TILE - 1) / TILE)   /* 394, last tile = 48 */

// IoU exactly as the numpy/JAX reference computes it (no FMA contraction:
// keep inter's rounding separate from the union subtraction).
__device__ __forceinline__ float iou_ref(float4 a, float4 b) {
#pragma clang fp contract(off)
  float ai = (a.z - a.x) * (a.w - a.y);
  float aj = (b.z - b.x) * (b.w - b.y);
  float ltx = fmaxf(a.x, b.x), lty = fmaxf(a.y, b.y);
  float rbx = fminf(a.z, b.z), rby = fminf(a.w, b.w);
  float wx = fmaxf(rbx - ltx, 0.0f), wy = fmaxf(rby - lty, 0.0f);
  float inter = wx * wy;
  return inter / (ai + aj - inter + EPS_F);
}

// K1: LDS-staged coalesced scoring (R4-proven), minus the global histogram
// (k2 now self-builds round 0 — removes ~300k contended global atomics and
// the hist memset dispatch).
// key = ordered(score)<<32 | (32767-n)<<7 | cls  (desc score, ties asc index)
__global__ __launch_bounds__(256) void k1_score(const float* __restrict__ pred,
                                                u64* __restrict__ keys) {
  __shared__ float srow[TILE * ROWF];     // 21760 B
  __shared__ u64 skeys[TILE];
  int tid = threadIdx.x;
  int b = blockIdx.y;
  int t0 = blockIdx.x * TILE;
  int ntile = (t0 + TILE <= NANCH) ? TILE : (NANCH - t0);   // 64 or 48
  int nf4 = (ntile * ROWF) >> 2;          // 1360 or 1020 (both exact)

  const float4* src4 = (const float4*)(pred + ((size_t)b * NANCH + t0) * ROWF);
  float4* smem4 = (float4*)srow;
#pragma unroll
  for (int k = 0; k < 6; ++k) {
    int i = k * 256 + tid;
    if (i < nf4) smem4[i] = src4[i];
  }
  __syncthreads();

  int a = tid >> 2;          // anchor in tile
  int q = tid & 3;           // class-quarter
  float best = -1e30f;
  int bidx = 0;
  float obj = 0.0f;
  if (a < ntile) {
    const float* row = srow + a * ROWF;
    obj = row[4];
    int c0 = q * 20;
#pragma unroll
    for (int c = 0; c < 20; ++c) {
      float s = row[5 + c0 + c] * obj;        // exact same mul as reference
      if (s > best) { best = s; bidx = c0 + c; }
    }
  }
  // exact tie rule: larger score wins; equal score -> lower class index wins
#pragma unroll
  for (int off = 1; off < 4; off <<= 1) {
    float ob = __shfl_xor(best, off);
    int oi = __shfl_xor(bidx, off);
    if (ob > best || (ob == best && oi < bidx)) { best = ob; bidx = oi; }
  }
  if (q == 0 && a < ntile) {
    int n = t0 + a;
    bool valid = (obj > CONF_T) && (best > CONF_T);
    u32 hi = valid ? (__float_as_uint(best) | 0x80000000u)  // ordered-float
                   : (((u32)n * 2654435761u) >> 1);         // spread, <0x8000..
    u32 lo = ((u32)(32767 - n) << 7) | (u32)bidx;
    skeys[a] = ((u64)hi << 32) | lo;
  }
  __syncthreads();
  if (tid < ntile) keys[(size_t)b * NANCH + t0 + tid] = skeys[tid];
}

// K2: exact top-1000. Radix 12+12+8 self-hist (verified bit-exact in R5's
// fused run), MLP-4 coalesced scans, two-level suffix select, compact,
// bitonic 2048, gather epilogue.
__global__ __launch_bounds__(1024) void k2_select(const float* __restrict__ pred,
                                                  const u64* __restrict__ keys,
                                                  float* __restrict__ selbox,
                                                  float* __restrict__ offbox,
                                                  float* __restrict__ selconf,
                                                  float* __restrict__ selcls,
                                                  u32* __restrict__ selvalid) {
  int b = blockIdx.x;
  int tid = threadIdx.x;
  int wv = tid >> 6, lane = tid & 63;
  __shared__ u32 h4[4096];
  __shared__ u64 skey[2048];
  __shared__ u32 wsum[16];
  __shared__ u32 sh_sel;
  __shared__ int sh_rank;
  __shared__ u32 scount;

  const u64* kb = keys + (size_t)b * NANCH;
  u32 prefix = 0;
  // ---- two 12-bit rounds ----
  for (int r = 0; r < 2; ++r) {
    for (int i = tid; i < 4096; i += 1024) h4[i] = 0;
    __syncthreads();
    for (int i0 = tid; i0 < NANCH; i0 += 4096) {
      int j1 = i0 + 1024, j2 = i0 + 2048, j3 = i0 + 3072;
      u64 k0 = kb[i0];
      u64 k1v = (j1 < NANCH) ? kb[j1] : 0;
      u64 k2v = (j2 < NANCH) ? kb[j2] : 0;
      u64 k3v = (j3 < NANCH) ? kb[j3] : 0;
      u32 h0 = (u32)(k0 >> 32), h1 = (u32)(k1v >> 32);
      u32 h2 = (u32)(k2v >> 32), h3 = (u32)(k3v >> 32);
      if (r == 0) {
        atomicAdd(&h4[h0 >> 20], 1u);
        if (j1 < NANCH) atomicAdd(&h4[h1 >> 20], 1u);
        if (j2 < NANCH) atomicAdd(&h4[h2 >> 20], 1u);
        if (j3 < NANCH) atomicAdd(&h4[h3 >> 20], 1u);
      } else {
        if ((h0 >> 20) == prefix) atomicAdd(&h4[(h0 >> 8) & 0xFFFu], 1u);
        if (j1 < NANCH && (h1 >> 20) == prefix) atomicAdd(&h4[(h1 >> 8) & 0xFFFu], 1u);
        if (j2 < NANCH && (h2 >> 20) == prefix) atomicAdd(&h4[(h2 >> 8) & 0xFFFu], 1u);
        if (j3 < NANCH && (h3 >> 20) == prefix) atomicAdd(&h4[(h3 >> 8) & 0xFFFu], 1u);
      }
    }
    __syncthreads();
    u32 a0 = h4[4 * tid], a1 = h4[4 * tid + 1], a2 = h4[4 * tid + 2], a3 = h4[4 * tid + 3];
    u32 lsum = a0 + a1 + a2 + a3;
    u32 suf = lsum;
#pragma unroll
    for (int off = 1; off < 64; off <<= 1) {
      u32 tv = __shfl_down(suf, off);
      if (lane + off < 64) suf += tv;
    }
    if (lane == 0) wsum[wv] = suf;
    int rank = (r == 0) ? MAXC : sh_rank;   // read BEFORE writers update
    __syncthreads();
    u32 base = 0;
#pragma unroll
    for (int w2 = 0; w2 < 16; ++w2) if (w2 > wv) base += wsum[w2];
    u32 e3 = base + suf - lsum; u32 i3v = e3 + a3;
    u32 e2 = i3v;               u32 i2v = e2 + a2;
    u32 e1 = i2v;               u32 i1v = e1 + a1;
    u32 e0 = i1v;               u32 i0v = e0 + a0;
    if ((int)i3v >= rank && (int)e3 < rank) { sh_sel = 4u*tid+3u; sh_rank = rank-(int)e3; }
    if ((int)i2v >= rank && (int)e2 < rank) { sh_sel = 4u*tid+2u; sh_rank = rank-(int)e2; }
    if ((int)i1v >= rank && (int)e1 < rank) { sh_sel = 4u*tid+1u; sh_rank = rank-(int)e1; }
    if ((int)i0v >= rank && (int)e0 < rank) { sh_sel = 4u*tid+0u; sh_rank = rank-(int)e0; }
    __syncthreads();
    prefix = (prefix << 12) | sh_sel;
  }
  // ---- final 8-bit round (256 bins, wave-0 select) ----
  if (tid < 256) h4[tid] = 0;
  __syncthreads();
  for (int i0 = tid; i0 < NANCH; i0 += 4096) {
    int j1 = i0 + 1024, j2 = i0 + 2048, j3 = i0 + 3072;
    u64 k0 = kb[i0];
    u64 k1v = (j1 < NANCH) ? kb[j1] : 0;
    u64 k2v = (j2 < NANCH) ? kb[j2] : 0;
    u64 k3v = (j3 < NANCH) ? kb[j3] : 0;
    u32 h0 = (u32)(k0 >> 32), h1 = (u32)(k1v >> 32);
    u32 h2 = (u32)(k2v >> 32), h3 = (u32)(k3v >> 32);
    if ((h0 >> 8) == prefix) atomicAdd(&h4[h0 & 0xFFu], 1u);
    if (j1 < NANCH && (h1 >> 8) == prefix) atomicAdd(&h4[h1 & 0xFFu], 1u);
    if (j2 < NANCH && (h2 >> 8) == prefix) atomicAdd(&h4[h2 & 0xFFu], 1u);
    if (j3 < NANCH && (h3 >> 8) == prefix) atomicAdd(&h4[h3 & 0xFFu], 1u);
  }
  __syncthreads();
  if (tid < 64) {
    int l = tid;
    u32 a0 = h4[4 * l], a1 = h4[4 * l + 1], a2 = h4[4 * l + 2], a3 = h4[4 * l + 3];
    u32 lsum = a0 + a1 + a2 + a3;
    u32 suf = lsum;
#pragma unroll
    for (int off = 1; off < 64; off <<= 1) {
      u32 tv = __shfl_down(suf, off);
      if (l + off < 64) suf += tv;
    }
    int rank = sh_rank;           // intra-wave: reads precede writes in order
    u32 e3 = suf - lsum; u32 i3v = e3 + a3;
    u32 e2 = i3v;        u32 i2v = e2 + a2;
    u32 e1 = i2v;        u32 i1v = e1 + a1;
    u32 e0 = i1v;        u32 i0v = e0 + a0;
    if ((int)i3v >= rank && (int)e3 < rank) { sh_sel = 4u*l+3u; }
    if ((int)i2v >= rank && (int)e2 < rank) { sh_sel = 4u*l+2u; }
    if ((int)i1v >= rank && (int)e1 < rank) { sh_sel = 4u*l+1u; }
    if ((int)i0v >= rank && (int)e0 < rank) { sh_sel = 4u*l+0u; }
  }
  __syncthreads();
  u32 Cstar = (prefix << 8) | sh_sel;

  // ---- compact (MLP-4) ----
  if (tid == 0) scount = 0;
  skey[tid] = ~0ull;
  skey[tid + 1024] = ~0ull;
  __syncthreads();
  for (int i0 = tid; i0 < NANCH; i0 += 4096) {
    int j1 = i0 + 1024, j2 = i0 + 2048, j3 = i0 + 3072;
    u64 k0 = kb[i0];
    u64 k1v = (j1 < NANCH) ? kb[j1] : 0;
    u64 k2v = (j2 < NANCH) ? kb[j2] : 0;
    u64 k3v = (j3 < NANCH) ? kb[j3] : 0;
    if ((u32)(k0 >> 32) >= Cstar) { u32 p = atomicAdd(&scount, 1u); if (p < 2048) skey[p] = ~k0; }
    if (j1 < NANCH && (u32)(k1v >> 32) >= Cstar) { u32 p = atomicAdd(&scount, 1u); if (p < 2048) skey[p] = ~k1v; }
    if (j2 < NANCH && (u32)(k2v >> 32) >= Cstar) { u32 p = atomicAdd(&scount, 1u); if (p < 2048) skey[p] = ~k2v; }
    if (j3 < NANCH && (u32)(k3v >> 32) >= Cstar) { u32 p = atomicAdd(&scount, 1u); if (p < 2048) skey[p] = ~k3v; }
  }
  __syncthreads();
  // ---- bitonic sort 2048 (ascending on ~key == descending key) ----
  for (u32 kk = 2; kk <= 2048; kk <<= 1) {
    for (u32 j = kk >> 1; j > 0; j >>= 1) {
      for (int idx = tid; idx < 2048; idx += 1024) {
        u32 ixj = (u32)idx ^ j;
        if (ixj > (u32)idx) {
          u64 a = skey[idx], c2 = skey[ixj];
          bool up = ((idx & kk) == 0);
          if (up ? (a > c2) : (a < c2)) { skey[idx] = c2; skey[ixj] = a; }
        }
      }
      __syncthreads();
    }
  }
  // ---- epilogue: gather + xywh2xyxy + class-offset boxes ----
  if (tid < MAXC) {
    u64 k = ~skey[tid];
    u32 hi = (u32)(k >> 32);
    u32 lo = (u32)k;
    u32 n = 32767u - (lo >> 7);
    u32 ci = lo & 127u;
    bool valid = hi > 0x80000000u;
    float conf = valid ? __uint_as_float(hi & 0x7FFFFFFFu) : 0.0f;
    const float* pr = pred + ((size_t)b * NANCH + n) * ROWF;
    float x = pr[0], y = pr[1], w = pr[2], h2 = pr[3];
    float x1 = x - w * 0.5f, y1 = y - h2 * 0.5f;
    float x2 = x + w * 0.5f, y2 = y + h2 * 0.5f;
    float cf = (float)ci;
    float off = cf * 4096.0f;
    int o = b * MAXC + tid;
    ((float4*)selbox)[o] = make_float4(x1, y1, x2, y2);
    ((float4*)offbox)[o] = make_float4(x1 + off, y1 + off, x2 + off, y2 + off);
    selconf[o] = conf;
    selcls[o] = cf;
    selvalid[o] = valid ? 1u : 0u;
  }
}

// K3: transposed suppression bits, stored WORD-MAJOR dt[b][w][i] so K4's
// 16-block load is coalesced (k3's 16-lane scatter is absorbed by its 16k
// waves of parallelism).
__global__ __launch_bounds__(256) void k3_dt(const float4* __restrict__ offbox4,
                                             u64* __restrict__ dt) {
  int wid = blockIdx.x * 4 + (threadIdx.x >> 6);   // b*MAXC + i
  int lane = threadIdx.x & 63;
  int b = wid / MAXC;
  int i = wid % MAXC;
  float4 bi = offbox4[b * MAXC + i];
  u64 myword = 0;
  for (int w = 0; w < 16; ++w) {
    int j = w * 64 + lane;
    int jc = (j < MAXC) ? j : 0;
    float4 bj = offbox4[b * MAXC + jc];
    float iou = iou_ref(bi, bj);
    bool bit = (iou > IOU_T) && (j < i);            // j<i implies j<MAXC
    u64 bal = __ballot(bit ? 1 : 0);
    if (lane == w) myword = bal;
  }
  if (lane < 16) dt[((size_t)b * 16 + lane) * MAXC + i] = myword;
}

// K4: Jacobi fixed-point of keep[i] = valid[i] & ~OR_{j<i}(keep[j]&D[j,i]).
// Unique fixed point == greedy NMS; converges in max-chain-depth passes.
__global__ __launch_bounds__(1024) void k4_jacobi(const u64* __restrict__ dt,
                                                  const u32* __restrict__ selvalid,
                                                  const float* __restrict__ selbox,
                                                  const float* __restrict__ selconf,
                                                  const float* __restrict__ selcls,
                                                  float* __restrict__ out) {
  int b = blockIdx.x;
  int tid = threadIdx.x;
  int wv = tid >> 6, lane = tid & 63;
  __shared__ u64 keepv[16];
  __shared__ u32 changed;
  bool valid = false;
  u64 dtr[16];
  if (tid < MAXC) {
    valid = selvalid[b * MAXC + tid] != 0u;
#pragma unroll
    for (int w = 0; w < 16; ++w) dtr[w] = dt[((size_t)b * 16 + w) * MAXC + tid];
  } else {
#pragma unroll
    for (int w = 0; w < 16; ++w) dtr[w] = 0ull;
  }
  u64 bal0 = __ballot(valid ? 1 : 0);
  if (tid == 0) changed = 0;
  if (lane == 0) keepv[wv] = bal0;
  __syncthreads();
  for (int pass = 0; pass < MAXC; ++pass) {
    u64 kv[16];
#pragma unroll
    for (int w = 0; w < 16; ++w) kv[w] = keepv[w];
    u64 s = 0;
#pragma unroll
    for (int w = 0; w < 16; ++w) s |= dtr[w] & kv[w];
    bool nk = valid && (s == 0ull);
    u64 bal = __ballot(nk ? 1 : 0);
    __syncthreads();                       // A: all keepv reads done
    if (lane == 0 && bal != kv[wv]) { keepv[wv] = bal; atomicOr(&changed, 1u); }
    __syncthreads();                       // B: writes visible
    u32 ch = changed;
    __syncthreads();                       // C: all read ch before reset
    if (tid == 0) changed = 0;
    if (!ch) break;                        // ch uniform -> uniform exit
  }
  if (tid < MAXC) {
    bool kept = ((keepv[wv] >> lane) & 1ull) != 0ull;
    size_t o = (size_t)b * MAXC + tid;
    float4 bx = ((const float4*)selbox)[o];
    float cf = selconf[o], cl = selcls[o];
    float* orow = out + o * 6;
    orow[0] = kept ? bx.x : 0.0f;
    orow[1] = kept ? bx.y : 0.0f;
    orow[2] = kept ? bx.z : 0.0f;
    orow[3] = kept ? bx.w : 0.0f;
    orow[4] = kept ? cf : 0.0f;
    orow[5] = kept ? cl : 0.0f;
    out[(size_t)BATCH * MAXC * 6 + o] = kept ? 1.0f : 0.0f;
  }
}

extern "C" void kernel_launch(void* const* d_in, const int* in_sizes, int n_in,
                              void* d_out, int out_size, void* d_ws, size_t ws_size,
                              hipStream_t stream) {
  const float* pred = (const float*)d_in[0];
  float* out = (float*)d_out;
  char* ws = (char*)d_ws;
  size_t off = 0;
  auto alloc = [&](size_t bytes) -> void* {
    void* p = ws + off;
    off = (off + bytes + 255) & ~(size_t)255;
    return p;
  };
  u64* keys     = (u64*)alloc((size_t)BATCH * NANCH * 8);
  float* selbox = (float*)alloc((size_t)BATCH * MAXC * 4 * 4);
  float* offbox = (float*)alloc((size_t)BATCH * MAXC * 4 * 4);
  float* selconf= (float*)alloc((size_t)BATCH * MAXC * 4);
  float* selcls = (float*)alloc((size_t)BATCH * MAXC * 4);
  u32* selvalid = (u32*)alloc((size_t)BATCH * MAXC * 4);
  u64* dt       = (u64*)alloc((size_t)BATCH * 16 * MAXC * 8);
  (void)ws_size; (void)in_sizes; (void)n_in; (void)out_size;

  dim3 g1(NTILES, BATCH);
  k1_score<<<g1, 256, 0, stream>>>(pred, keys);
  k2_select<<<BATCH, 1024, 0, stream>>>(pred, keys, selbox, offbox,
                                        selconf, selcls, selvalid);
  k3_dt<<<(BATCH * MAXC) / 4, 256, 0, stream>>>((const float4*)offbox, dt);
  k4_jacobi<<<BATCH, 1024, 0, stream>>>(dt, selvalid, selbox, selconf,
                                        selcls, out);
}

// Round 7
// 244.542 us; speedup vs baseline: 2.5001x; 1.1023x over previous
//
#include <hip/hip_runtime.h>
#include <stdint.h>

typedef unsigned int u32;
typedef unsigned long long u64;

#define BATCH 16
#define NANCH 25200
#define NCLS 80
#define ROWF 85
#define MAXC 1000
#define CONF_T 0.25f
#define IOU_T 0.45f
#define EPS_F 1e-7f
#define TILE 64
#define NTILES ((NANCH + TILE - 1) / TILE)   /* 394, last tile = 48 */

// IoU exactly as the numpy/JAX reference computes it (no FMA contraction:
// keep inter's rounding separate from the union subtraction).
__device__ __forceinline__ float iou_ref(float4 a, float4 b) {
#pragma clang fp contract(off)
  float ai = (a.z - a.x) * (a.w - a.y);
  float aj = (b.z - b.x) * (b.w - b.y);
  float ltx = fmaxf(a.x, b.x), lty = fmaxf(a.y, b.y);
  float rbx = fminf(a.z, b.z), rby = fminf(a.w, b.w);
  float wx = fmaxf(rbx - ltx, 0.0f), wy = fmaxf(rby - lty, 0.0f);
  float inter = wx * wy;
  return inter / (ai + aj - inter + EPS_F);
}

// K1: LDS-staged coalesced scoring. Emits 32-bit keys:
//   valid:   (conf_bits - 0x3E800000) << 7 | cls   (conf in (0.25,1) => 24-bit
//            rebased value; monotone in conf; >= 0x80)
//   invalid: 0
__global__ __launch_bounds__(256) void k1_score(const float* __restrict__ pred,
                                                u32* __restrict__ keys32) {
  __shared__ float srow[TILE * ROWF];     // 21760 B
  __shared__ u32 skeys[TILE];
  int tid = threadIdx.x;
  int b = blockIdx.y;
  int t0 = blockIdx.x * TILE;
  int ntile = (t0 + TILE <= NANCH) ? TILE : (NANCH - t0);   // 64 or 48
  int nf4 = (ntile * ROWF) >> 2;          // 1360 or 1020 (both exact)

  const float4* src4 = (const float4*)(pred + ((size_t)b * NANCH + t0) * ROWF);
  float4* smem4 = (float4*)srow;
#pragma unroll
  for (int k = 0; k < 6; ++k) {
    int i = k * 256 + tid;
    if (i < nf4) smem4[i] = src4[i];
  }
  __syncthreads();

  int a = tid >> 2;          // anchor in tile
  int q = tid & 3;           // class-quarter
  float best = -1e30f;
  int bidx = 0;
  float obj = 0.0f;
  if (a < ntile) {
    const float* row = srow + a * ROWF;
    obj = row[4];
    int c0 = q * 20;
#pragma unroll
    for (int c = 0; c < 20; ++c) {
      float s = row[5 + c0 + c] * obj;        // exact same mul as reference
      if (s > best) { best = s; bidx = c0 + c; }
    }
  }
  // exact tie rule: larger score wins; equal score -> lower class index wins
#pragma unroll
  for (int off = 1; off < 4; off <<= 1) {
    float ob = __shfl_xor(best, off);
    int oi = __shfl_xor(bidx, off);
    if (ob > best || (ob == best && oi < bidx)) { best = ob; bidx = oi; }
  }
  if (q == 0 && a < ntile) {
    bool valid = (obj > CONF_T) && (best > CONF_T);
    u32 k = valid ? (((__float_as_uint(best) - 0x3E800000u) << 7) | (u32)bidx)
                  : 0u;
    skeys[a] = k;
  }
  __syncthreads();
  if (tid < ntile) keys32[(size_t)b * NANCH + t0 + tid] = skeys[tid];
}

// K2: top-1000 via ONE 13-bit histogram pass (bin-floor cut = conservative
// superset of the exact top-1000; boundary bin holds ~1-2 keys for this
// input), keys cached in 25 registers/thread (single global read), compact,
// bitonic sort of reconstructed exact 64-bit order keys
// (conf_rebased<<32 | (32767-i)<<7 | cls), gather epilogue.
__global__ __launch_bounds__(1024) void k2_select(const float* __restrict__ pred,
                                                  const u32* __restrict__ keys32,
                                                  float* __restrict__ selbox,
                                                  float* __restrict__ offbox,
                                                  float2* __restrict__ selmeta) {
  int b = blockIdx.x;
  int tid = threadIdx.x;
  int wv = tid >> 6, lane = tid & 63;
  __shared__ u32 h[8192];          // 32 KB
  __shared__ u64 skey[2048];       // 16 KB
  __shared__ u32 wsum[16];
  __shared__ u32 sh_fbin;
  __shared__ u32 scount;

  const u32* kb = keys32 + (size_t)b * NANCH;
  u32 kreg[25];
#pragma unroll
  for (int j = 0; j < 25; ++j) {
    int i = tid + j * 1024;
    kreg[j] = (i < NANCH) ? kb[i] : 0u;    // only j==24 can be OOB
  }
  for (int i = tid; i < 8192; i += 1024) h[i] = 0;
  if (tid == 0) { sh_fbin = 0; scount = 0; }
  skey[tid] = ~0ull;
  skey[tid + 1024] = ~0ull;
  __syncthreads();
#pragma unroll
  for (int j = 0; j < 25; ++j) {
    u32 k = kreg[j];
    if (k >= 0x80u) atomicAdd(&h[k >> 18], 1u);   // valid keys only
  }
  __syncthreads();
  // suffix-sum select over 8192 bins (8 per thread): smallest bin f with
  // count(keys in bins >= f) >= 1000
  u32 a[8]; u32 lsum = 0;
#pragma unroll
  for (int k = 0; k < 8; ++k) { a[k] = h[8 * tid + k]; lsum += a[k]; }
  u32 suf = lsum;
#pragma unroll
  for (int off = 1; off < 64; off <<= 1) {
    u32 tv = __shfl_down(suf, off);
    if (lane + off < 64) suf += tv;
  }
  if (lane == 0) wsum[wv] = suf;
  __syncthreads();
  u32 base = 0;
#pragma unroll
  for (int w2 = 0; w2 < 16; ++w2) if (w2 > wv) base += wsum[w2];
  u32 e = base + suf - lsum;       // count of keys in bins strictly above 8t+7
#pragma unroll
  for (int k = 7; k >= 0; --k) {
    u32 inc = e + a[k];
    if ((int)inc >= MAXC && (int)e < MAXC) sh_fbin = (u32)(8 * tid + k);
    e = inc;
  }
  __syncthreads();
  u32 cut = sh_fbin << 18;
  // compact from registers; reconstruct exact order key
#pragma unroll
  for (int j = 0; j < 25; ++j) {
    u32 k = kreg[j];
    if (k >= cut && k != 0u) {
      int i = tid + j * 1024;
      u64 sk = ((u64)(k >> 7) << 32) |
               (u64)(((32767u - (u32)i) << 7) | (k & 127u));
      u32 p = atomicAdd(&scount, 1u);
      if (p < 2048) skey[p] = ~sk;   // ascending on ~key == descending key
    }
  }
  __syncthreads();
  int n = (scount <= 1024u) ? 1024 : 2048;   // uniform branch; 1024 typical
  for (u32 kk = 2; kk <= (u32)n; kk <<= 1) {
    for (u32 j = kk >> 1; j > 0; j >>= 1) {
      for (int idx = tid; idx < n; idx += 1024) {
        u32 ixj = (u32)idx ^ j;
        if (ixj > (u32)idx) {
          u64 x = skey[idx], y = skey[ixj];
          bool up = ((idx & kk) == 0);
          if (up ? (x > y) : (x < y)) { skey[idx] = y; skey[ixj] = x; }
        }
      }
      __syncthreads();
    }
  }
  // epilogue: gather + xywh2xyxy + class-offset boxes
  if (tid < MAXC) {
    u64 k = ~skey[tid];
    u32 confpart = (u32)(k >> 32);
    u32 lo = (u32)k;
    bool valid = confpart != 0u;     // pad and invalid both give 0
    float conf = 0.0f, x1 = 0.0f, y1 = 0.0f, x2 = 0.0f, y2 = 0.0f;
    float cf = 0.0f, offv = 0.0f;
    if (valid) {
      u32 nidx = 32767u - ((lo >> 7) & 0x7FFFu);
      u32 ci = lo & 127u;
      conf = __uint_as_float(confpart + 0x3E800000u);   // exact bits restored
      const float* pr = pred + ((size_t)b * NANCH + nidx) * ROWF;
      float x = pr[0], y = pr[1], w = pr[2], h2 = pr[3];
      x1 = x - w * 0.5f; y1 = y - h2 * 0.5f;
      x2 = x + w * 0.5f; y2 = y + h2 * 0.5f;
      cf = (float)ci; offv = cf * 4096.0f;
    }
    int o = b * MAXC + tid;
    ((float4*)selbox)[o] = make_float4(x1, y1, x2, y2);
    // invalid rows: zero box (IoU vs anything = 0 < 0.45, and keep=false
    // rows never suppress — matches reference semantics)
    ((float4*)offbox)[o] = make_float4(x1 + offv, y1 + offv, x2 + offv, y2 + offv);
    selmeta[o] = make_float2(conf, cf);
  }
}

// K3: transposed suppression bits, stored WORD-MAJOR dt[b][w][i] so K4's
// 16-block load is coalesced.
__global__ __launch_bounds__(256) void k3_dt(const float4* __restrict__ offbox4,
                                             u64* __restrict__ dt) {
  int wid = blockIdx.x * 4 + (threadIdx.x >> 6);   // b*MAXC + i
  int lane = threadIdx.x & 63;
  int b = wid / MAXC;
  int i = wid % MAXC;
  float4 bi = offbox4[b * MAXC + i];
  u64 myword = 0;
  for (int w = 0; w < 16; ++w) {
    int j = w * 64 + lane;
    int jc = (j < MAXC) ? j : 0;
    float4 bj = offbox4[b * MAXC + jc];
    float iou = iou_ref(bi, bj);
    bool bit = (iou > IOU_T) && (j < i);            // j<i implies j<MAXC
    u64 bal = __ballot(bit ? 1 : 0);
    if (lane == w) myword = bal;
  }
  if (lane < 16) dt[((size_t)b * 16 + lane) * MAXC + i] = myword;
}

// K4: Jacobi fixed-point of keep[i] = valid[i] & ~OR_{j<i}(keep[j]&D[j,i]).
// Unique fixed point == greedy NMS; converges in max-chain-depth passes.
__global__ __launch_bounds__(1024) void k4_jacobi(const u64* __restrict__ dt,
                                                  const float2* __restrict__ selmeta,
                                                  const float* __restrict__ selbox,
                                                  float* __restrict__ out) {
  int b = blockIdx.x;
  int tid = threadIdx.x;
  int wv = tid >> 6, lane = tid & 63;
  __shared__ u64 keepv[16];
  __shared__ u32 changed;
  bool valid = false;
  float2 meta = make_float2(0.0f, 0.0f);
  u64 dtr[16];
  if (tid < MAXC) {
    meta = selmeta[b * MAXC + tid];
    valid = meta.x > 0.0f;                 // conf>0 <=> valid
#pragma unroll
    for (int w = 0; w < 16; ++w) dtr[w] = dt[((size_t)b * 16 + w) * MAXC + tid];
  } else {
#pragma unroll
    for (int w = 0; w < 16; ++w) dtr[w] = 0ull;
  }
  u64 bal0 = __ballot(valid ? 1 : 0);
  if (tid == 0) changed = 0;
  if (lane == 0) keepv[wv] = bal0;
  __syncthreads();
  for (int pass = 0; pass < MAXC; ++pass) {
    u64 kv[16];
#pragma unroll
    for (int w = 0; w < 16; ++w) kv[w] = keepv[w];
    u64 s = 0;
#pragma unroll
    for (int w = 0; w < 16; ++w) s |= dtr[w] & kv[w];
    bool nk = valid && (s == 0ull);
    u64 bal = __ballot(nk ? 1 : 0);
    __syncthreads();                       // A: all keepv reads done
    if (lane == 0 && bal != kv[wv]) { keepv[wv] = bal; atomicOr(&changed, 1u); }
    __syncthreads();                       // B: writes visible
    u32 ch = changed;
    __syncthreads();                       // C: all read ch before reset
    if (tid == 0) changed = 0;
    if (!ch) break;                        // ch uniform -> uniform exit
  }
  if (tid < MAXC) {
    bool kept = ((keepv[wv] >> lane) & 1ull) != 0ull;
    size_t o = (size_t)b * MAXC + tid;
    float4 bx = ((const float4*)selbox)[o];
    float* orow = out + o * 6;
    orow[0] = kept ? bx.x : 0.0f;
    orow[1] = kept ? bx.y : 0.0f;
    orow[2] = kept ? bx.z : 0.0f;
    orow[3] = kept ? bx.w : 0.0f;
    orow[4] = kept ? meta.x : 0.0f;
    orow[5] = kept ? meta.y : 0.0f;
    out[(size_t)BATCH * MAXC * 6 + o] = kept ? 1.0f : 0.0f;
  }
}

extern "C" void kernel_launch(void* const* d_in, const int* in_sizes, int n_in,
                              void* d_out, int out_size, void* d_ws, size_t ws_size,
                              hipStream_t stream) {
  const float* pred = (const float*)d_in[0];
  float* out = (float*)d_out;
  char* ws = (char*)d_ws;
  size_t off = 0;
  auto alloc = [&](size_t bytes) -> void* {
    void* p = ws + off;
    off = (off + bytes + 255) & ~(size_t)255;
    return p;
  };
  u32* keys32   = (u32*)alloc((size_t)BATCH * NANCH * 4);
  float* selbox = (float*)alloc((size_t)BATCH * MAXC * 4 * 4);
  float* offbox = (float*)alloc((size_t)BATCH * MAXC * 4 * 4);
  float2* selmeta = (float2*)alloc((size_t)BATCH * MAXC * 8);
  u64* dt       = (u64*)alloc((size_t)BATCH * 16 * MAXC * 8);
  (void)ws_size; (void)in_sizes; (void)n_in; (void)out_size;

  dim3 g1(NTILES, BATCH);
  k1_score<<<g1, 256, 0, stream>>>(pred, keys32);
  k2_select<<<BATCH, 1024, 0, stream>>>(pred, keys32, selbox, offbox, selmeta);
  k3_dt<<<(BATCH * MAXC) / 4, 256, 0, stream>>>((const float4*)offbox, dt);
  k4_jacobi<<<BATCH, 1024, 0, stream>>>(dt, selmeta, selbox, out);
}

// Round 8
// 241.351 us; speedup vs baseline: 2.5332x; 1.0132x over previous
//
#include <hip/hip_runtime.h>
#include <stdint.h>

typedef unsigned int u32;
typedef unsigned long long u64;

#define BATCH 16
#define NANCH 25200
#define NCLS 80
#define ROWF 85
#define MAXC 1000
#define CONF_T 0.25f
#define IOU_T 0.45f
#define EPS_F 1e-7f
#define TILE 64
#define NTILES ((NANCH + TILE - 1) / TILE)   /* 394, last tile = 48 */

// IoU exactly as the numpy/JAX reference computes it (no FMA contraction:
// keep inter's rounding separate from the union subtraction).
__device__ __forceinline__ float iou_ref(float4 a, float4 b) {
#pragma clang fp contract(off)
  float ai = (a.z - a.x) * (a.w - a.y);
  float aj = (b.z - b.x) * (b.w - b.y);
  float ltx = fmaxf(a.x, b.x), lty = fmaxf(a.y, b.y);
  float rbx = fminf(a.z, b.z), rby = fminf(a.w, b.w);
  float wx = fmaxf(rbx - ltx, 0.0f), wy = fmaxf(rby - lty, 0.0f);
  float inter = wx * wy;
  return inter / (ai + aj - inter + EPS_F);
}

// K1: LDS-staged coalesced scoring. Emits 32-bit keys:
//   valid:   (conf_bits - 0x3E800000) << 7 | cls   (conf in (0.25,1) => 24-bit
//            rebased value; monotone in conf; >= 0x80)
//   invalid: 0
__global__ __launch_bounds__(256) void k1_score(const float* __restrict__ pred,
                                                u32* __restrict__ keys32) {
  __shared__ float srow[TILE * ROWF];     // 21760 B
  __shared__ u32 skeys[TILE];
  int tid = threadIdx.x;
  int b = blockIdx.y;
  int t0 = blockIdx.x * TILE;
  int ntile = (t0 + TILE <= NANCH) ? TILE : (NANCH - t0);   // 64 or 48
  int nf4 = (ntile * ROWF) >> 2;          // 1360 or 1020 (both exact)

  const float4* src4 = (const float4*)(pred + ((size_t)b * NANCH + t0) * ROWF);
  float4* smem4 = (float4*)srow;
#pragma unroll
  for (int k = 0; k < 6; ++k) {
    int i = k * 256 + tid;
    if (i < nf4) smem4[i] = src4[i];
  }
  __syncthreads();

  int a = tid >> 2;          // anchor in tile
  int q = tid & 3;           // class-quarter
  float best = -1e30f;
  int bidx = 0;
  float obj = 0.0f;
  if (a < ntile) {
    const float* row = srow + a * ROWF;
    obj = row[4];
    int c0 = q * 20;
#pragma unroll
    for (int c = 0; c < 20; ++c) {
      float s = row[5 + c0 + c] * obj;        // exact same mul as reference
      if (s > best) { best = s; bidx = c0 + c; }
    }
  }
  // exact tie rule: larger score wins; equal score -> lower class index wins
#pragma unroll
  for (int off = 1; off < 4; off <<= 1) {
    float ob = __shfl_xor(best, off);
    int oi = __shfl_xor(bidx, off);
    if (ob > best || (ob == best && oi < bidx)) { best = ob; bidx = oi; }
  }
  if (q == 0 && a < ntile) {
    bool valid = (obj > CONF_T) && (best > CONF_T);
    u32 k = valid ? (((__float_as_uint(best) - 0x3E800000u) << 7) | (u32)bidx)
                  : 0u;
    skeys[a] = k;
  }
  __syncthreads();
  if (tid < ntile) keys32[(size_t)b * NANCH + t0 + tid] = skeys[tid];
}

// K2: top-1000 via ONE 13-bit histogram pass (bin-floor cut = conservative
// superset of the exact top-1000), keys cached in 25 registers/thread,
// compact, bitonic sort of exact 64-bit order keys. n==1024 path sorts in
// REGISTERS: shfl_xor for intra-wave strides (45 phases, no barrier), LDS
// round-trip only for the 10 cross-wave phases.
__global__ __launch_bounds__(1024) void k2_select(const float* __restrict__ pred,
                                                  const u32* __restrict__ keys32,
                                                  float* __restrict__ selbox,
                                                  float* __restrict__ offbox,
                                                  float2* __restrict__ selmeta) {
  int b = blockIdx.x;
  int tid = threadIdx.x;
  int wv = tid >> 6, lane = tid & 63;
  __shared__ u32 h[8192];          // 32 KB
  __shared__ u64 skey[2048];       // 16 KB
  __shared__ u32 wsum[16];
  __shared__ u32 sh_fbin;
  __shared__ u32 scount;

  const u32* kb = keys32 + (size_t)b * NANCH;
  u32 kreg[25];
#pragma unroll
  for (int j = 0; j < 25; ++j) {
    int i = tid + j * 1024;
    kreg[j] = (i < NANCH) ? kb[i] : 0u;    // only j==24 can be OOB
  }
  for (int i = tid; i < 8192; i += 1024) h[i] = 0;
  if (tid == 0) { sh_fbin = 0; scount = 0; }
  skey[tid] = ~0ull;
  skey[tid + 1024] = ~0ull;
  __syncthreads();
#pragma unroll
  for (int j = 0; j < 25; ++j) {
    u32 k = kreg[j];
    if (k >= 0x80u) atomicAdd(&h[k >> 18], 1u);   // valid keys only
  }
  __syncthreads();
  // suffix-sum select over 8192 bins (8 per thread): smallest bin f with
  // count(keys in bins >= f) >= 1000
  u32 a[8]; u32 lsum = 0;
#pragma unroll
  for (int k = 0; k < 8; ++k) { a[k] = h[8 * tid + k]; lsum += a[k]; }
  u32 suf = lsum;
#pragma unroll
  for (int off = 1; off < 64; off <<= 1) {
    u32 tv = __shfl_down(suf, off);
    if (lane + off < 64) suf += tv;
  }
  if (lane == 0) wsum[wv] = suf;
  __syncthreads();
  u32 base = 0;
#pragma unroll
  for (int w2 = 0; w2 < 16; ++w2) if (w2 > wv) base += wsum[w2];
  u32 e = base + suf - lsum;       // count of keys in bins strictly above 8t+7
#pragma unroll
  for (int k = 7; k >= 0; --k) {
    u32 inc = e + a[k];
    if ((int)inc >= MAXC && (int)e < MAXC) sh_fbin = (u32)(8 * tid + k);
    e = inc;
  }
  __syncthreads();
  u32 cut = sh_fbin << 18;
  // compact from registers; reconstruct exact order key
#pragma unroll
  for (int j = 0; j < 25; ++j) {
    u32 k = kreg[j];
    if (k >= cut && k != 0u) {
      int i = tid + j * 1024;
      u64 sk = ((u64)(k >> 7) << 32) |
               (u64)(((32767u - (u32)i) << 7) | (k & 127u));
      u32 p = atomicAdd(&scount, 1u);
      if (p < 2048) skey[p] = ~sk;   // ascending on ~key == descending key
    }
  }
  __syncthreads();
  u64 v;                                     // this thread's sorted element
  if (scount <= 1024u) {
    // ---- register bitonic over 1024 (one element/thread) ----
    v = skey[tid];
    for (u32 kk = 2; kk <= 1024; kk <<= 1) {
      for (u32 j = kk >> 1; j > 0; j >>= 1) {
        bool up = ((tid & kk) == 0);         // ascending segment
        bool low = ((tid & j) == 0);         // this thread is the low index
        if (j >= 64) {
          skey[tid] = v;
          __syncthreads();
          u64 o = skey[tid ^ j];
          bool takemin = (up == low);
          v = takemin ? (v < o ? v : o) : (v > o ? v : o);
          __syncthreads();                   // protect skey before next store
        } else {
          u64 o = __shfl_xor(v, (int)j);
          bool takemin = (up == low);
          v = takemin ? (v < o ? v : o) : (v > o ? v : o);
        }
      }
    }
  } else {
    // ---- fallback: in-LDS bitonic over 2048 ----
    for (u32 kk = 2; kk <= 2048; kk <<= 1) {
      for (u32 j = kk >> 1; j > 0; j >>= 1) {
        for (int idx = tid; idx < 2048; idx += 1024) {
          u32 ixj = (u32)idx ^ j;
          if (ixj > (u32)idx) {
            u64 x = skey[idx], y = skey[ixj];
            bool up = ((idx & kk) == 0);
            if (up ? (x > y) : (x < y)) { skey[idx] = y; skey[ixj] = x; }
          }
        }
        __syncthreads();
      }
    }
    v = skey[tid];
  }
  // epilogue: gather + xywh2xyxy + class-offset boxes
  if (tid < MAXC) {
    u64 k = ~v;
    u32 confpart = (u32)(k >> 32);
    u32 lo = (u32)k;
    bool valid = confpart != 0u;     // pad and invalid both give 0
    float conf = 0.0f, x1 = 0.0f, y1 = 0.0f, x2 = 0.0f, y2 = 0.0f;
    float cf = 0.0f, offv = 0.0f;
    if (valid) {
      u32 nidx = 32767u - ((lo >> 7) & 0x7FFFu);
      u32 ci = lo & 127u;
      conf = __uint_as_float(confpart + 0x3E800000u);   // exact bits restored
      const float* pr = pred + ((size_t)b * NANCH + nidx) * ROWF;
      float x = pr[0], y = pr[1], w = pr[2], h2 = pr[3];
      x1 = x - w * 0.5f; y1 = y - h2 * 0.5f;
      x2 = x + w * 0.5f; y2 = y + h2 * 0.5f;
      cf = (float)ci; offv = cf * 4096.0f;
    }
    int o = b * MAXC + tid;
    ((float4*)selbox)[o] = make_float4(x1, y1, x2, y2);
    ((float4*)offbox)[o] = make_float4(x1 + offv, y1 + offv, x2 + offv, y2 + offv);
    selmeta[o] = make_float2(conf, cf);
  }
}

// K3: transposed suppression bits, stored WORD-MAJOR dt[b][w][i] so K4's
// 16-block load is coalesced.
__global__ __launch_bounds__(256) void k3_dt(const float4* __restrict__ offbox4,
                                             u64* __restrict__ dt) {
  int wid = blockIdx.x * 4 + (threadIdx.x >> 6);   // b*MAXC + i
  int lane = threadIdx.x & 63;
  int b = wid / MAXC;
  int i = wid % MAXC;
  float4 bi = offbox4[b * MAXC + i];
  u64 myword = 0;
  for (int w = 0; w < 16; ++w) {
    int j = w * 64 + lane;
    int jc = (j < MAXC) ? j : 0;
    float4 bj = offbox4[b * MAXC + jc];
    float iou = iou_ref(bi, bj);
    bool bit = (iou > IOU_T) && (j < i);            // j<i implies j<MAXC
    u64 bal = __ballot(bit ? 1 : 0);
    if (lane == w) myword = bal;
  }
  if (lane < 16) dt[((size_t)b * 16 + lane) * MAXC + i] = myword;
}

// K4: Jacobi fixed-point of keep[i] = valid[i] & ~OR_{j<i}(keep[j]&D[j,i]).
// Unique fixed point == greedy NMS; converges in max-chain-depth passes.
// 2 barriers/pass via double-buffered changed flags.
__global__ __launch_bounds__(1024) void k4_jacobi(const u64* __restrict__ dt,
                                                  const float2* __restrict__ selmeta,
                                                  const float* __restrict__ selbox,
                                                  float* __restrict__ out) {
  int b = blockIdx.x;
  int tid = threadIdx.x;
  int wv = tid >> 6, lane = tid & 63;
  __shared__ u64 keepv[16];
  __shared__ u32 changed2[2];
  bool valid = false;
  float2 meta = make_float2(0.0f, 0.0f);
  u64 dtr[16];
  if (tid < MAXC) {
    meta = selmeta[b * MAXC + tid];
    valid = meta.x > 0.0f;                 // conf>0 <=> valid
#pragma unroll
    for (int w = 0; w < 16; ++w) dtr[w] = dt[((size_t)b * 16 + w) * MAXC + tid];
  } else {
#pragma unroll
    for (int w = 0; w < 16; ++w) dtr[w] = 0ull;
  }
  u64 bal0 = __ballot(valid ? 1 : 0);
  if (tid == 0) { changed2[0] = 0; changed2[1] = 0; }
  if (lane == 0) keepv[wv] = bal0;
  __syncthreads();
  for (int pass = 0; pass < MAXC; ++pass) {
    u64 kv[16];
#pragma unroll
    for (int w = 0; w < 16; ++w) kv[w] = keepv[w];
    u64 s = 0;
#pragma unroll
    for (int w = 0; w < 16; ++w) s |= dtr[w] & kv[w];
    bool nk = valid && (s == 0ull);
    u64 bal = __ballot(nk ? 1 : 0);
    __syncthreads();                       // A: all keepv/flag reads done
    if (lane == 0 && bal != kv[wv]) {
      keepv[wv] = bal;
      atomicOr(&changed2[pass & 1], 1u);
    }
    __syncthreads();                       // B: writes visible
    u32 ch = changed2[pass & 1];
    if (tid == 0) changed2[(pass & 1) ^ 1] = 0;  // reset OTHER slot (consumed
                                                 // last pass; reuse in 2)
    if (!ch) break;                        // ch uniform -> uniform exit
  }
  if (tid < MAXC) {
    bool kept = ((keepv[wv] >> lane) & 1ull) != 0ull;
    size_t o = (size_t)b * MAXC + tid;
    float4 bx = ((const float4*)selbox)[o];
    float* orow = out + o * 6;
    orow[0] = kept ? bx.x : 0.0f;
    orow[1] = kept ? bx.y : 0.0f;
    orow[2] = kept ? bx.z : 0.0f;
    orow[3] = kept ? bx.w : 0.0f;
    orow[4] = kept ? meta.x : 0.0f;
    orow[5] = kept ? meta.y : 0.0f;
    out[(size_t)BATCH * MAXC * 6 + o] = kept ? 1.0f : 0.0f;
  }
}

extern "C" void kernel_launch(void* const* d_in, const int* in_sizes, int n_in,
                              void* d_out, int out_size, void* d_ws, size_t ws_size,
                              hipStream_t stream) {
  const float* pred = (const float*)d_in[0];
  float* out = (float*)d_out;
  char* ws = (char*)d_ws;
  size_t off = 0;
  auto alloc = [&](size_t bytes) -> void* {
    void* p = ws + off;
    off = (off + bytes + 255) & ~(size_t)255;
    return p;
  };
  u32* keys32   = (u32*)alloc((size_t)BATCH * NANCH * 4);
  float* selbox = (float*)alloc((size_t)BATCH * MAXC * 4 * 4);
  float* offbox = (float*)alloc((size_t)BATCH * MAXC * 4 * 4);
  float2* selmeta = (float2*)alloc((size_t)BATCH * MAXC * 8);
  u64* dt       = (u64*)alloc((size_t)BATCH * 16 * MAXC * 8);
  (void)ws_size; (void)in_sizes; (void)n_in; (void)out_size;

  dim3 g1(NTILES, BATCH);
  k1_score<<<g1, 256, 0, stream>>>(pred, keys32);
  k2_select<<<BATCH, 1024, 0, stream>>>(pred, keys32, selbox, offbox, selmeta);
  k3_dt<<<(BATCH * MAXC) / 4, 256, 0, stream>>>((const float4*)offbox, dt);
  k4_jacobi<<<BATCH, 1024, 0, stream>>>(dt, selmeta, selbox, out);
}